// Round 5
// baseline (5156.589 us; speedup 1.0000x reference)
//
#include <hip/hip_runtime.h>

#define VD 128
#define HD 1024
#define BD 64
#define TD 256
#define NB 256

typedef __bf16 bf16;
typedef __bf16 bf16x8 __attribute__((ext_vector_type(8)));
typedef __bf16 bf16x4 __attribute__((ext_vector_type(4)));
typedef float f32x4 __attribute__((ext_vector_type(4)));

// ---- ws layout (byte offsets) ----
#define OFF_OUTS 0ull                           // bf16 [T][B][H]   33,554,432 B
#define OFF_XW   33554432ull                    // bf16 [T][B][V]    4,194,304 B
#define OFF_WA1  (OFF_XW  + 4194304ull)         // bf16 [4H][V]      1,048,576 B
#define OFF_WA2  (OFF_WA1 + 1048576ull)         // bf16 [4H][H]      8,388,608 B
#define OFF_WB1  (OFF_WA2 + 8388608ull)         // bf16 [4H][H]
#define OFF_WB2  (OFF_WB1 + 8388608ull)         // bf16 [4H][H]
#define OFF_WFC  (OFF_WB2 + 8388608ull)         // bf16 [V][H]         262,144 B
#define OFF_BUFA (OFF_WFC + 262144ull)          // bf16 [2][B][H]      262,144 B
#define OFF_BUFB (OFF_BUFA + 262144ull)
#define OFF_CAF  (OFF_BUFB + 262144ull)         // fp32 [B][H]
#define OFF_CBF  (OFF_CAF + 262144ull)

struct Params {
  const bf16 *x, *WA1, *WA2, *WB1, *WB2;  // bf16 canonical (ws)
  const float *bA1, *bA2, *bB1, *bB2;     // fp32 biases (inputs)
  bf16 *bufA, *bufB, *outs;
  float *cA, *cB;
};

__device__ __forceinline__ bf16x8 ld8(const bf16* p) {
  return *reinterpret_cast<const bf16x8*>(p);
}
__device__ __forceinline__ float sigf(float x) { return 1.f / (1.f + __expf(-x)); }

// fp32 -> bf16 staging: x, WA1, WA2, WB1, WB2, Wfc. 4 elems/thread via float4.
__global__ void conv_k(const float* x, const float* WA1, const float* WA2,
                       const float* WB1, const float* WB2, const float* Wfc,
                       char* ws) {
  const size_t g4 = (size_t)blockIdx.x * 256 + threadIdx.x;
  size_t i = g4 * 4;
  const float* src;
  bf16* dst;
  size_t off;
  if (i < 2097152ull)        { src = x;   dst = (bf16*)(ws + OFF_XW);  off = i; }
  else if (i < 2621440ull)   { src = WA1; dst = (bf16*)(ws + OFF_WA1); off = i - 2097152ull; }
  else if (i < 6815744ull)   { src = WA2; dst = (bf16*)(ws + OFF_WA2); off = i - 2621440ull; }
  else if (i < 11010048ull)  { src = WB1; dst = (bf16*)(ws + OFF_WB1); off = i - 6815744ull; }
  else if (i < 15204352ull)  { src = WB2; dst = (bf16*)(ws + OFF_WB2); off = i - 11010048ull; }
  else if (i < 15335424ull)  { src = Wfc; dst = (bf16*)(ws + OFF_WFC); off = i - 15204352ull; }
  else return;
  float4 v = *reinterpret_cast<const float4*>(src + off);
  bf16x4 o = { (bf16)v.x, (bf16)v.y, (bf16)v.z, (bf16)v.w };
  *reinterpret_cast<bf16x4*>(dst + off) = o;
}

__global__ void init_k(const float* hA, const float* cA, const float* hB, const float* cB,
                       char* ws) {
  int i = blockIdx.x * 256 + threadIdx.x;  // 65536 = B*H
  ((bf16*)(ws + OFF_BUFA))[i] = (bf16)hA[i];
  ((bf16*)(ws + OFF_BUFB))[i] = (bf16)hB[i];
  ((float*)(ws + OFF_CAF))[i] = cA[i];
  ((float*)(ws + OFF_CBF))[i] = cB[i];
}

// One pipeline phase t: A-step t (t<T) + B-step t-1 (t>=1). Kernel boundaries
// (stream order) provide device-wide coherence between phases.
// Block bk owns h-columns j0..j0+3 of BOTH cells (16 gate rows each).
// Waves: wv>>2 = cell (0=A,1=B), wv&3 = K-quarter. mfma_f32_16x16x32_bf16,
// partials -> LDS -> 512-thread elementwise gate update.
__global__ void __launch_bounds__(512) phase_k(Params p, int t) {
  __shared__ float part[8][16][65];
  const int tid = threadIdx.x;
  const int wv = tid >> 6, lane = tid & 63;
  const int lrow = lane & 15, q = lane >> 4;
  const int j0 = blockIdx.x * 4;
  const int cs = wv >> 2, kq = wv & 3;
  const int gate = lrow >> 2, jj = lrow & 3;
  const int grow = gate * HD + j0 + jj;

  const bf16 *w1, *w2;
  if (cs == 0) { w1 = p.WA1 + grow * VD + q * 8; w2 = p.WA2 + (size_t)grow * HD + q * 8; }
  else         { w1 = p.WB1 + (size_t)grow * HD + q * 8; w2 = p.WB2 + (size_t)grow * HD + q * 8; }

  const bool active = (cs == 0) ? (t < TD) : (t >= 1);
  const bf16* hA = p.bufA + ((t & 1) ? (size_t)BD * HD : 0);
  if (active) {
    f32x4 acc[4] = {};
    if (cs == 0) {
      // K-chain 1152 = x(128) + hA(1024); quarter kq = [kq*288, kq*288+288)
      if (kq == 0) {
        const bf16* xb = p.x + (size_t)t * BD * VD + q * 8;
#pragma unroll
        for (int s = 0; s < 4; s++) {
          bf16x8 bfv = ld8(w1 + s * 32);
          const bf16* ap = xb + s * 32;
#pragma unroll
          for (int m = 0; m < 4; m++) {
            bf16x8 afv = ld8(ap + (m * 16 + lrow) * VD);
            acc[m] = __builtin_amdgcn_mfma_f32_16x16x32_bf16(afv, bfv, acc[m], 0, 0, 0);
          }
        }
      }
      const int hk0 = (kq == 0) ? 0 : kq * 288 - 128;
      const int nh = (kq == 0) ? 5 : 9;
#pragma unroll 3
      for (int s = 0; s < nh; s++) {
        int hk = hk0 + s * 32;
        bf16x8 bfv = ld8(w2 + hk);
        const bf16* ap = hA + hk + q * 8;
#pragma unroll
        for (int m = 0; m < 4; m++) {
          bf16x8 afv = ld8(ap + (size_t)(m * 16 + lrow) * HD);
          acc[m] = __builtin_amdgcn_mfma_f32_16x16x32_bf16(afv, bfv, acc[m], 0, 0, 0);
        }
      }
    } else {
      // K-chain 2048 = hA@WB1 (0..1023) + hB@WB2 (1024..2047); quarter = 512
      const bf16* hB = p.bufB + (((t - 1) & 1) ? (size_t)BD * HD : 0);
      const bf16* hp = (kq < 2) ? hA : hB;
      const bf16* wp = (kq < 2) ? w1 : w2;
      const int k0 = (kq & 1) * 512;
#pragma unroll 4
      for (int s = 0; s < 16; s++) {
        int hk = k0 + s * 32;
        bf16x8 bfv = ld8(wp + hk);
        const bf16* ap = hp + hk + q * 8;
#pragma unroll
        for (int m = 0; m < 4; m++) {
          bf16x8 afv = ld8(ap + (size_t)(m * 16 + lrow) * HD);
          acc[m] = __builtin_amdgcn_mfma_f32_16x16x32_bf16(afv, bfv, acc[m], 0, 0, 0);
        }
      }
    }
    // D layout: col(N)=lane&15, row(M)=q*4+r  [m89-verified]
#pragma unroll
    for (int m = 0; m < 4; m++)
#pragma unroll
      for (int r = 0; r < 4; r++)
        part[wv][lrow][m * 16 + q * 4 + r] = acc[m][r];
  }
  __syncthreads();

  // elementwise: tid 0..255 -> cell A, 256..511 -> cell B; (batch=tid&63, jj=(tid>>6)&3)
  const int eb = tid & 63;
  const int ejj = (tid >> 6) & 3;
  const int ecs = tid >> 8;
  const int ej = j0 + ejj;
  const int eidx = eb * HD + ej;
  const bool ew = (ecs == 0) ? (t < TD) : (t >= 1);
  if (ew) {
    const float* b1 = ecs ? p.bB1 : p.bA1;
    const float* b2 = ecs ? p.bB2 : p.bA2;
    float* ec = ecs ? p.cB : p.cA;
    const int wb = ecs * 4;
    float g4[4];
#pragma unroll
    for (int g = 0; g < 4; g++) {
      int n = g * 4 + ejj;
      g4[g] = b1[g * HD + ej] + b2[g * HD + ej] + part[wb + 0][n][eb] +
              part[wb + 1][n][eb] + part[wb + 2][n][eb] + part[wb + 3][n][eb];
    }
    float cold = ec[eidx];
    float cn = sigf(g4[1]) * cold + sigf(g4[0]) * tanhf(g4[2]);
    float hn = sigf(g4[3]) * tanhf(cn);
    ec[eidx] = cn;
    if (ecs == 0) {
      p.bufA[(((t + 1) & 1) ? (size_t)BD * HD : 0) + eidx] = (bf16)hn;
    } else {
      p.bufB[((t & 1) ? (size_t)BD * HD : 0) + eidx] = (bf16)hn;
      p.outs[((size_t)(t - 1) * BD + eb) * HD + ej] = (bf16)hn;
    }
  }
}

// out[T*B, V] = outs[T*B, H] @ Wfc[V, H]^T + bfc.  OUTPUT IS FP32.
__global__ void fc_k(const bf16* outs, const bf16* Wfc, const float* bfc, float* out) {
  const int tid = threadIdx.x;
  const int wv = tid >> 6, lane = tid & 63;
  const int lrow = lane & 15, q = lane >> 4;
  const int row0 = blockIdx.x * 64 + wv * 16;
  const bf16* arow = outs + (size_t)(row0 + lrow) * HD + q * 8;
  const bf16* wrow[8];
#pragma unroll
  for (int ct = 0; ct < 8; ct++) wrow[ct] = Wfc + (size_t)(ct * 16 + lrow) * HD + q * 8;
  f32x4 acc[8] = {};
#pragma unroll 2
  for (int s = 0; s < 32; s++) {
    bf16x8 afv = ld8(arow + s * 32);
#pragma unroll
    for (int ct = 0; ct < 8; ct++) {
      bf16x8 bfv = ld8(wrow[ct] + s * 32);
      acc[ct] = __builtin_amdgcn_mfma_f32_16x16x32_bf16(afv, bfv, acc[ct], 0, 0, 0);
    }
  }
#pragma unroll
  for (int ct = 0; ct < 8; ct++) {
    float bv = bfc[ct * 16 + lrow];
#pragma unroll
    for (int r = 0; r < 4; r++)
      out[(size_t)(row0 + q * 4 + r) * VD + ct * 16 + lrow] = acc[ct][r] + bv;
  }
}

// final states: (hA, cA, hB, cB) appended after out[T*B,V], FP32.
__global__ void tail_k(const char* ws, float* out) {
  int i = blockIdx.x * 256 + threadIdx.x;  // 65536
  float* o = out + (size_t)TD * BD * VD;
  o[i]             = (float)((const bf16*)(ws + OFF_BUFA))[i];  // hA final: parity 0
  o[65536 + i]     = ((const float*)(ws + OFF_CAF))[i];
  o[2 * 65536 + i] = (float)((const bf16*)(ws + OFF_BUFB))[i];  // hB final: parity 0
  o[3 * 65536 + i] = ((const float*)(ws + OFF_CBF))[i];
}

extern "C" void kernel_launch(void* const* d_in, const int* in_sizes, int n_in,
                              void* d_out, int out_size, void* d_ws, size_t ws_size,
                              hipStream_t stream) {
  const float* x   = (const float*)d_in[0];
  const float* hA  = (const float*)d_in[1];
  const float* cA  = (const float*)d_in[2];
  const float* hB  = (const float*)d_in[3];
  const float* cB  = (const float*)d_in[4];
  const float* WA1 = (const float*)d_in[5];
  const float* bA1 = (const float*)d_in[6];
  const float* WA2 = (const float*)d_in[7];
  const float* bA2 = (const float*)d_in[8];
  const float* WB1 = (const float*)d_in[9];
  const float* bB1 = (const float*)d_in[10];
  const float* WB2 = (const float*)d_in[11];
  const float* bB2 = (const float*)d_in[12];
  const float* Wfc = (const float*)d_in[13];
  const float* bfc = (const float*)d_in[14];

  char* ws = (char*)d_ws;

  conv_k<<<(15335424 / 4 + 255) / 256, 256, 0, stream>>>(x, WA1, WA2, WB1, WB2, Wfc, ws);
  init_k<<<256, 256, 0, stream>>>(hA, cA, hB, cB, ws);

  Params p{(const bf16*)(ws + OFF_XW), (const bf16*)(ws + OFF_WA1),
           (const bf16*)(ws + OFF_WA2), (const bf16*)(ws + OFF_WB1),
           (const bf16*)(ws + OFF_WB2),
           bA1, bA2, bB1, bB2,
           (bf16*)(ws + OFF_BUFA), (bf16*)(ws + OFF_BUFB), (bf16*)(ws + OFF_OUTS),
           (float*)(ws + OFF_CAF), (float*)(ws + OFF_CBF)};

  // 257 stream-ordered phases: kernel boundaries = device-wide coherence.
  for (int t = 0; t <= TD; t++) {
    phase_k<<<NB, 512, 0, stream>>>(p, t);
  }

  fc_k<<<256, 256, 0, stream>>>((const bf16*)(ws + OFF_OUTS), (const bf16*)(ws + OFF_WFC),
                                bfc, (float*)d_out);
  tail_k<<<256, 256, 0, stream>>>(ws, (float*)d_out);
}